// Round 8
// baseline (66.060 us; speedup 1.0000x reference)
//
#include <hip/hip_runtime.h>
#include <cstdint>
#include <cstddef>

#define TINV 5.0f
#define C5L2E 7.2134752044448170f   // 5 * log2(e)
#define NROWS 4096
#define DDIM 256
#define MM 8192

typedef __bf16 bf16x8 __attribute__((ext_vector_type(8)));
typedef int i32x4 __attribute__((ext_vector_type(4)));
typedef float f32x4 __attribute__((ext_vector_type(4)));

typedef const void __attribute__((address_space(1)))* gas_ptr;
typedef void __attribute__((address_space(3)))* las_ptr;

// ------- normalize rows of [Z1;Z2] -> unit L2, store bf16 -------
__global__ __launch_bounds__(256, 2)
void nrm_kernel(const float* __restrict__ Z1, const float* __restrict__ Z2,
                unsigned short* __restrict__ Zb) {
    const int w = threadIdx.x >> 6, lane = threadIdx.x & 63;
    const int row = blockIdx.x * 4 + w;
    const float* src = row < NROWS ? Z1 + (size_t)row * DDIM
                                   : Z2 + (size_t)(row - NROWS) * DDIM;
    float4 v = reinterpret_cast<const float4*>(src)[lane];
    float ss = v.x*v.x + v.y*v.y + v.z*v.z + v.w*v.w;
    #pragma unroll
    for (int m = 1; m < 64; m <<= 1) ss += __shfl_xor(ss, m, 64);
    float inv = 1.0f / fmaxf(sqrtf(ss), 1e-12f);
    float o[4] = { v.x*inv, v.y*inv, v.z*inv, v.w*inv };
    unsigned short us[4];
    #pragma unroll
    for (int e = 0; e < 4; ++e) {           // RNE f32->bf16 (finite inputs)
        unsigned int b = __builtin_bit_cast(unsigned int, o[e]);
        b += 0x7FFFu + ((b >> 16) & 1u);
        us[e] = (unsigned short)(b >> 16);
    }
    reinterpret_cast<ushort4*>(Zb + (size_t)row * DDIM)[lane] =
        *reinterpret_cast<ushort4*>(us);
}

// ---- stage 64 rows x 512B (32KB) into LDS with 256 threads; source pre-swizzled ----
// read side uses phys_inrow = inrow ^ ((row&15)<<4)
__device__ __forceinline__ void stage32(const unsigned short* Zb, char* ldsdst,
                                        int rowStart, int tid) {
    const char* base = reinterpret_cast<const char*>(Zb) + (size_t)rowStart * 512;
    #pragma unroll
    for (int it = 0; it < 8; ++it) {
        int L = it * 4096 + tid * 16;     // linear LDS byte offset, lane-contiguous
        int row = L >> 9;                 // 0..63
        int soff = row * 512 + ((L & 511) ^ ((row & 15) << 4));
        __builtin_amdgcn_global_load_lds((gas_ptr)(base + soff), (las_ptr)(ldsdst + L),
                                         16, 0, 0);
    }
}

// -------- symmetric fused sim + exp-rowsum/colsum + pos extraction --------
// 64 bands x 128 rows; block (r,s): d = s+8k (k=0..3), each d-tile 128x128 done as
// 2 x 64-col subtiles; d=0 diag (rowsum, skip i==j); d>=1 rowsum+colsum (symmetry);
// d=32 halves assigned to splits e0/e1, rowsum-only, pos col i^4096 lives there.
// 4 waves as 2x2: wave = (wr row-group of 64 rows [A in AGPR], wc col-half of 32).
// NO atomics: colsums -> colPartT[(d-1)*2+wr][j], rowsums -> rowPart[s*2+wc][i],
// every slot written exactly once (dense), reduced in fin1.
__global__ __launch_bounds__(256, 2)
void sim_lse_kernel(const unsigned short* __restrict__ Zb,
                    float* __restrict__ rowPart,    // [16][MM]
                    float* __restrict__ colPartT,   // [62][MM]
                    float* __restrict__ posArr) {   // [MM]
    __shared__ char lds[65536];                     // 2 x 32KB B buffers
    const int tid = threadIdx.x;
    const int lane = tid & 63;
    const int w = tid >> 6;
    const int wr = w >> 1, wc = w & 1;              // row-group 0..1? (see below)
    const int r15 = lane & 15, hi = lane >> 4;
    const int r = blockIdx.x >> 3;                  // band 0..63
    const int s = blockIdx.x & 7;                   // split 0..7
    const int R0 = r * 128;
    const int e0 = r & 7, e1 = e0 ^ 4;
    const int nt = 8 + ((s == e0) || (s == e1));
    const int extraHalf = (s == e1) ? 1 : 0;

    // subtile t -> column start (row units of Zb)
    auto colOf = [&](int t) -> int {
        if (t == 8) return ((r + 32) & 63) * 128 + extraHalf * 64;
        int d = s + ((t >> 1) << 3);
        return ((r + d) & 63) * 128 + (t & 1) * 64;
    };

    stage32(Zb, lds, colOf(0), tid);                // subtile 0 -> buf0

    // ---- A fragments: 64 rows x K=256 straight from global into AGPRs ----
    i32x4 qf[4][8];
    {
        const char* abase = reinterpret_cast<const char*>(Zb)
                          + (size_t)(R0 + wr * 64 + r15) * 512 + hi * 16;
        #pragma unroll
        for (int mf = 0; mf < 4; ++mf)
            #pragma unroll
            for (int kk = 0; kk < 8; ++kk)
                qf[mf][kk] = *reinterpret_cast<const i32x4*>(abase + mf * 8192 + kk * 64);
    }

    // thread-constant swizzled B-frag offsets (row&15 == r15 always)
    int baddr[8];
    #pragma unroll
    for (int kk = 0; kk < 8; ++kk)
        baddr[kk] = (wc * 32 + r15) * 512 + (((hi << 4) | (kk << 6)) ^ (r15 << 4));

    float rowsum[4][4] = {{0,0,0,0},{0,0,0,0},{0,0,0,0},{0,0,0,0}};
    const int iBase = R0 + wr * 64 + (hi << 2);     // C/D: row=(lane>>4)*4+rr

    for (int t = 0; t < nt; ++t) {
        const int C0 = colOf(t);
        const int cur = (t & 1) << 15;
        if (t < nt - 1) {
            stage32(Zb, lds + (cur ^ 32768), colOf(t + 1), tid);
            asm volatile("s_waitcnt vmcnt(8)" ::: "memory");   // cur's 8 loads done
        } else {
            asm volatile("s_waitcnt vmcnt(0)" ::: "memory");
        }
        __builtin_amdgcn_s_barrier();
        __builtin_amdgcn_sched_barrier(0);

        const int mode = (t == 8) ? 2 : ((s == 0 && t < 2) ? 1 : 0); // 0 norm,1 diag,2 pos
        const int d = s + ((t >> 1) << 3);
        #pragma unroll
        for (int nf = 0; nf < 2; ++nf) {
            f32x4 acc[4] = {{0,0,0,0},{0,0,0,0},{0,0,0,0},{0,0,0,0}};
            #pragma unroll
            for (int kk = 0; kk < 8; ++kk) {
                i32x4 b = *reinterpret_cast<const i32x4*>(lds + cur + nf * 8192 + baddr[kk]);
                #pragma unroll
                for (int mf = 0; mf < 4; ++mf)
                    asm("v_mfma_f32_16x16x32_bf16 %0, %1, %2, %0"
                        : "+v"(acc[mf]) : "a"(qf[mf][kk]), "v"(b));
            }
            const int j = C0 + wc * 32 + nf * 16 + r15;   // C/D: col=lane&15
            if (mode == 0) {
                float s8 = 0.f;
                #pragma unroll
                for (int mf = 0; mf < 4; ++mf)
                    #pragma unroll
                    for (int rr = 0; rr < 4; ++rr) {
                        float e = __builtin_amdgcn_exp2f(fmaf(acc[mf][rr], C5L2E, -C5L2E));
                        rowsum[mf][rr] += e;
                        s8 += e;
                    }
                s8 += __shfl_xor(s8, 16, 64);       // sum 4 hi-groups => 64 rows
                s8 += __shfl_xor(s8, 32, 64);
                if (hi == 0)
                    colPartT[(size_t)(((d - 1) << 1) | wr) * MM + j] = s8;  // unique
            } else if (mode == 1) {
                #pragma unroll
                for (int mf = 0; mf < 4; ++mf)
                    #pragma unroll
                    for (int rr = 0; rr < 4; ++rr) {
                        const int i = iBase + mf * 16 + rr;
                        if (j != i)
                            rowsum[mf][rr] += __builtin_amdgcn_exp2f(fmaf(acc[mf][rr], C5L2E, -C5L2E));
                    }
            } else {
                #pragma unroll
                for (int mf = 0; mf < 4; ++mf)
                    #pragma unroll
                    for (int rr = 0; rr < 4; ++rr) {
                        const int i = iBase + mf * 16 + rr;
                        rowsum[mf][rr] += __builtin_amdgcn_exp2f(fmaf(acc[mf][rr], C5L2E, -C5L2E));
                        if (j == (i ^ 4096)) posArr[i] = acc[mf][rr] * TINV;  // unique
                    }
            }
        }
        asm volatile("" ::: "memory");
        __builtin_amdgcn_sched_barrier(0);
        __builtin_amdgcn_s_barrier();               // done reading cur before overwrite
    }

    // reduce rowsums across the 16 lanes sharing each row; unique slot per (s,wc)
    #pragma unroll
    for (int mf = 0; mf < 4; ++mf)
        #pragma unroll
        for (int rr = 0; rr < 4; ++rr) {
            float v = rowsum[mf][rr];
            v += __shfl_xor(v, 1, 64);
            v += __shfl_xor(v, 2, 64);
            v += __shfl_xor(v, 4, 64);
            v += __shfl_xor(v, 8, 64);
            if (r15 == 0)
                rowPart[(size_t)((s << 1) | wc) * MM + iBase + mf * 16 + rr] = v;
        }
}

// ---------------- finish: lse = log(sum)+5; mean(lse - pos) ----------------
__global__ __launch_bounds__(128)
void fin1_kernel(const float* __restrict__ rowPart, const float* __restrict__ colPartT,
                 const float* __restrict__ posArr, float* __restrict__ blockSums) {
    const int tid = threadIdx.x;
    const int i = blockIdx.x * 128 + tid;
    float se = 0.f;
    #pragma unroll
    for (int p = 0; p < 16; ++p) se += rowPart[(size_t)p * MM + i];
    #pragma unroll
    for (int q = 0; q < 62; ++q) se += colPartT[(size_t)q * MM + i];
    double v = (double)(logf(se) + 5.0f - posArr[i]);
    #pragma unroll
    for (int m = 1; m < 64; m <<= 1) v += __shfl_xor(v, m, 64);
    __shared__ double red[2];
    if ((tid & 63) == 0) red[tid >> 6] = v;
    __syncthreads();
    if (tid == 0) blockSums[blockIdx.x] = (float)(red[0] + red[1]);
}

__global__ __launch_bounds__(64)
void fin2_kernel(const float* __restrict__ blockSums, float* __restrict__ out) {
    double v = (double)blockSums[threadIdx.x];
    #pragma unroll
    for (int m = 1; m < 64; m <<= 1) v += __shfl_xor(v, m, 64);
    if (threadIdx.x == 0) out[0] = (float)(v / (double)MM);
}

extern "C" void kernel_launch(void* const* d_in, const int* in_sizes, int n_in,
                              void* d_out, int out_size, void* d_ws, size_t ws_size,
                              hipStream_t stream) {
    const float* Z1 = (const float*)d_in[0];
    const float* Z2 = (const float*)d_in[1];
    float* out = (float*)d_out;
    char* ws = (char*)d_ws;
    unsigned short* Zb = (unsigned short*)ws;                 // 4 MB bf16 [8192][256]
    float* posArr   = (float*)(ws + 4194304);                 // 32 KB
    float* rowPart  = (float*)(ws + 4194304 + 32768);         // 16 x 32 KB
    float* colPartT = (float*)(ws + 4194304 + 32768 + 524288);// 62 x 32 KB
    float* blockSums= (float*)(ws + 4194304 + 32768 + 524288 + 2031616); // 256 B

    nrm_kernel<<<MM / 4, 256, 0, stream>>>(Z1, Z2, Zb);
    sim_lse_kernel<<<64 * 8, 256, 0, stream>>>(Zb, rowPart, colPartT, posArr);
    fin1_kernel<<<64, 128, 0, stream>>>(rowPart, colPartT, posArr, blockSums);
    fin2_kernel<<<1, 64, 0, stream>>>(blockSums, out);
}

// Round 9
// 46.032 us; speedup vs baseline: 1.4351x; 1.4351x over previous
//
#include <hip/hip_runtime.h>
#include <cstdint>
#include <cstddef>

#define TINV 5.0f
#define C5L2E 7.2134752044448170f   // 5 * log2(e)
#define NROWS 4096
#define DDIM 256
#define MM 8192

typedef __bf16 bf16x8 __attribute__((ext_vector_type(8)));
typedef float f32x4 __attribute__((ext_vector_type(4)));

typedef const void __attribute__((address_space(1)))* gas_ptr;
typedef void __attribute__((address_space(3)))* las_ptr;

// ------- normalize rows of [Z1;Z2] -> unit L2, store bf16; zero rowsumAcc -------
__global__ __launch_bounds__(256, 2)
void nrm_kernel(const float* __restrict__ Z1, const float* __restrict__ Z2,
                unsigned short* __restrict__ Zb, float* __restrict__ rowsumAcc) {
    if (blockIdx.x < 32) rowsumAcc[blockIdx.x * 256 + threadIdx.x] = 0.f;
    const int w = threadIdx.x >> 6, lane = threadIdx.x & 63;
    const int row = blockIdx.x * 4 + w;
    const float* src = row < NROWS ? Z1 + (size_t)row * DDIM
                                   : Z2 + (size_t)(row - NROWS) * DDIM;
    float4 v = reinterpret_cast<const float4*>(src)[lane];
    float ss = v.x*v.x + v.y*v.y + v.z*v.z + v.w*v.w;
    #pragma unroll
    for (int m = 1; m < 64; m <<= 1) ss += __shfl_xor(ss, m, 64);
    float inv = 1.0f / fmaxf(sqrtf(ss), 1e-12f);
    float o[4] = { v.x*inv, v.y*inv, v.z*inv, v.w*inv };
    unsigned short us[4];
    #pragma unroll
    for (int e = 0; e < 4; ++e) {           // RNE f32->bf16 (finite inputs)
        unsigned int b = __builtin_bit_cast(unsigned int, o[e]);
        b += 0x7FFFu + ((b >> 16) & 1u);
        us[e] = (unsigned short)(b >> 16);
    }
    reinterpret_cast<ushort4*>(Zb + (size_t)row * DDIM)[lane] =
        *reinterpret_cast<ushort4*>(us);
}

// ---- stage 32 rows x 512B (16KB) into LDS with 256 threads; source pre-swizzled ----
// read side uses phys_inrow = inrow ^ ((row&15)<<4)
__device__ __forceinline__ void stage16(const unsigned short* Zb, char* ldsdst,
                                        int rowStart, int tid) {
    const char* base = reinterpret_cast<const char*>(Zb) + (size_t)rowStart * 512;
    #pragma unroll
    for (int it = 0; it < 4; ++it) {
        int L = it * 4096 + tid * 16;     // linear LDS byte offset, lane-contiguous
        int row = L >> 9;                 // 0..31
        int soff = row * 512 + ((L & 511) ^ ((row & 15) << 4));
        __builtin_amdgcn_global_load_lds((gas_ptr)(base + soff), (las_ptr)(ldsdst + L),
                                         16, 0, 0);
    }
}

// -------- symmetric fused sim + exp-rowsum/colsum + pos extraction --------
// 64 bands x 128 rows, 16 splits -> 1024 blocks = 4/CU (16 waves/CU).
// Block (r,s): d = s (t=0..3) and d = s+16 (t=4..7), 32-col quarters q = t&3;
// d=0 (s==0) diag: rowsum, skip i==j; d>=1: rowsum AND colsum (symmetry);
// d=32 quarters assigned to the 4 splits with s&3==r&3 (q=s>>2), rowsum-only,
// pos col i^4096 lives there. 4 waves, each owns 32 rows (A-frags from global,
// kept in VGPRs), all waves share the 32-col B subtile (16KB, double-buffered).
__global__ __launch_bounds__(256, 4)
void sim_lse_kernel(const unsigned short* __restrict__ Zb,
                    float* __restrict__ rowsumAcc,  // [MM], atomic accum
                    float* __restrict__ posArr) {   // [MM]
    __shared__ char lds[32768];                     // 2 x 16KB B buffers
    __shared__ float colRed[4][32];
    const int tid = threadIdx.x;
    const int lane = tid & 63;
    const int w = tid >> 6;
    const int r15 = lane & 15, hi = lane >> 4;
    const int r = blockIdx.x >> 4;                  // band 0..63
    const int s = blockIdx.x & 15;                  // split 0..15
    const int R0 = r * 128;
    const bool hasExtra = (s & 3) == (r & 3);
    const int q32 = s >> 2;                         // which d=32 quarter
    const int nt = hasExtra ? 9 : 8;

    // subtile t -> column start (row units of Zb)
    auto colOf = [&](int t) -> int {
        if (t == 8) return ((r + 32) & 63) * 128 + q32 * 32;
        int d = (t < 4) ? s : s + 16;
        return ((r + d) & 63) * 128 + (t & 3) * 32;
    };

    stage16(Zb, lds, colOf(0), tid);                // subtile 0 -> buf0

    // ---- A fragments: wave's 32 rows x K=256 from global (plain layout) ----
    bf16x8 qf[2][8];
    {
        const char* abase = reinterpret_cast<const char*>(Zb)
                          + (size_t)(R0 + w * 32 + r15) * 512 + hi * 16;
        #pragma unroll
        for (int mf = 0; mf < 2; ++mf)
            #pragma unroll
            for (int kk = 0; kk < 8; ++kk)
                qf[mf][kk] = *reinterpret_cast<const bf16x8*>(abase + mf * 8192 + kk * 64);
    }

    // thread-constant swizzled B-frag offsets (buf row = nf*16 + r15, row&15 == r15)
    int baddr[8];
    #pragma unroll
    for (int kk = 0; kk < 8; ++kk)
        baddr[kk] = r15 * 512 + (((hi << 4) | (kk << 6)) ^ (r15 << 4));

    float rowsum[2][4] = {{0,0,0,0},{0,0,0,0}};
    const int iBase = R0 + w * 32 + (hi << 2);      // C/D: row=(lane>>4)*4+rr

    for (int t = 0; t < nt; ++t) {
        const int C0 = colOf(t);
        char* curb = lds + ((t & 1) << 14);
        // did the PREVIOUS phase issue a colsum atomic? (it sits in vmcnt queue)
        const bool pf = (t > 0) && !(s == 0 && t < 5) && (t != 9);
        if (t < nt - 1) {
            stage16(Zb, lds + (((t & 1) ^ 1) << 14), colOf(t + 1), tid);
            if (pf) asm volatile("s_waitcnt vmcnt(5)" ::: "memory"); // skip prev atomic
            else    asm volatile("s_waitcnt vmcnt(4)" ::: "memory");
        } else {
            asm volatile("s_waitcnt vmcnt(0)" ::: "memory");
        }
        __builtin_amdgcn_s_barrier();
        __builtin_amdgcn_sched_barrier(0);

        const int mode = (t == 8) ? 2 : ((s == 0 && t < 4) ? 1 : 0); // 0 norm,1 diag,2 pos
        #pragma unroll
        for (int nf = 0; nf < 2; ++nf) {
            f32x4 acc0 = {0,0,0,0}, acc1 = {0,0,0,0};
            #pragma unroll
            for (int kk = 0; kk < 8; ++kk) {
                bf16x8 b = *reinterpret_cast<const bf16x8*>(curb + nf * 8192 + baddr[kk]);
                acc0 = __builtin_amdgcn_mfma_f32_16x16x32_bf16(qf[0][kk], b, acc0, 0, 0, 0);
                acc1 = __builtin_amdgcn_mfma_f32_16x16x32_bf16(qf[1][kk], b, acc1, 0, 0, 0);
            }
            const int j = C0 + nf * 16 + r15;       // C/D: col=lane&15
            if (mode == 0) {
                float s8 = 0.f;
                #pragma unroll
                for (int mf = 0; mf < 2; ++mf) {
                    const f32x4 a = mf ? acc1 : acc0;
                    #pragma unroll
                    for (int rr = 0; rr < 4; ++rr) {
                        float e = __builtin_amdgcn_exp2f(fmaf(a[rr], C5L2E, -C5L2E));
                        rowsum[mf][rr] += e;
                        s8 += e;
                    }
                }
                s8 += __shfl_xor(s8, 16, 64);       // sum 4 hi-groups => 32 rows
                s8 += __shfl_xor(s8, 32, 64);
                if (hi == 0) colRed[w][nf * 16 + r15] = s8;
            } else if (mode == 1) {
                #pragma unroll
                for (int mf = 0; mf < 2; ++mf) {
                    const f32x4 a = mf ? acc1 : acc0;
                    #pragma unroll
                    for (int rr = 0; rr < 4; ++rr) {
                        const int i = iBase + mf * 16 + rr;
                        if (j != i)
                            rowsum[mf][rr] += __builtin_amdgcn_exp2f(fmaf(a[rr], C5L2E, -C5L2E));
                    }
                }
            } else {
                #pragma unroll
                for (int mf = 0; mf < 2; ++mf) {
                    const f32x4 a = mf ? acc1 : acc0;
                    #pragma unroll
                    for (int rr = 0; rr < 4; ++rr) {
                        const int i = iBase + mf * 16 + rr;
                        rowsum[mf][rr] += __builtin_amdgcn_exp2f(fmaf(a[rr], C5L2E, -C5L2E));
                        if (j == (i ^ 4096)) posArr[i] = a[rr] * TINV;  // unique writer
                    }
                }
            }
        }
        asm volatile("s_waitcnt lgkmcnt(0)" ::: "memory");  // colRed writes visible
        __builtin_amdgcn_sched_barrier(0);
        __builtin_amdgcn_s_barrier();               // done reading cur before overwrite

        // flush colsums of this 32-col subtile to partner band rows (symmetry)
        if (mode == 0 && tid < 32) {
            float v = colRed[0][tid] + colRed[1][tid] + colRed[2][tid] + colRed[3][tid];
            atomicAdd(&rowsumAcc[C0 + tid], v);
        }
    }

    // reduce rowsums across the 16 lanes sharing each row, flush atomically
    #pragma unroll
    for (int mf = 0; mf < 2; ++mf)
        #pragma unroll
        for (int rr = 0; rr < 4; ++rr) {
            float v = rowsum[mf][rr];
            v += __shfl_xor(v, 1, 64);
            v += __shfl_xor(v, 2, 64);
            v += __shfl_xor(v, 4, 64);
            v += __shfl_xor(v, 8, 64);
            if (r15 == 0) atomicAdd(&rowsumAcc[iBase + mf * 16 + rr], v);
        }
}

// ---------------- finish: lse = log(sum)+5; mean(lse - pos) ----------------
__global__ __launch_bounds__(128)
void fin1_kernel(const float* __restrict__ rowsumAcc, const float* __restrict__ posArr,
                 float* __restrict__ blockSums) {    // [64]
    const int tid = threadIdx.x;
    const int i = blockIdx.x * 128 + tid;
    double v = (double)(logf(rowsumAcc[i]) + 5.0f - posArr[i]);
    #pragma unroll
    for (int m = 1; m < 64; m <<= 1) v += __shfl_xor(v, m, 64);
    __shared__ double red[2];
    if ((tid & 63) == 0) red[tid >> 6] = v;
    __syncthreads();
    if (tid == 0) blockSums[blockIdx.x] = (float)(red[0] + red[1]);
}

__global__ __launch_bounds__(64)
void fin2_kernel(const float* __restrict__ blockSums, float* __restrict__ out) {
    double v = (double)blockSums[threadIdx.x];
    #pragma unroll
    for (int m = 1; m < 64; m <<= 1) v += __shfl_xor(v, m, 64);
    if (threadIdx.x == 0) out[0] = (float)(v / (double)MM);
}

extern "C" void kernel_launch(void* const* d_in, const int* in_sizes, int n_in,
                              void* d_out, int out_size, void* d_ws, size_t ws_size,
                              hipStream_t stream) {
    const float* Z1 = (const float*)d_in[0];
    const float* Z2 = (const float*)d_in[1];
    float* out = (float*)d_out;
    char* ws = (char*)d_ws;
    unsigned short* Zb = (unsigned short*)ws;                         // 4 MB bf16 [8192][256]
    float* posArr = (float*)(ws + 4194304);                           // 32 KB
    float* rowsumAcc = (float*)(ws + 4194304 + 32768);                // 32 KB
    float* blockSums = (float*)(ws + 4194304 + 65536);                // 256 B

    nrm_kernel<<<MM / 4, 256, 0, stream>>>(Z1, Z2, Zb, rowsumAcc);
    sim_lse_kernel<<<64 * 16, 256, 0, stream>>>(Zb, rowsumAcc, posArr);
    fin1_kernel<<<64, 128, 0, stream>>>(rowsumAcc, posArr, blockSums);
    fin2_kernel<<<1, 64, 0, stream>>>(blockSums, out);
}

// Round 10
// 43.314 us; speedup vs baseline: 1.5251x; 1.0628x over previous
//
#include <hip/hip_runtime.h>
#include <cstdint>
#include <cstddef>

#define TINV 5.0f
#define C5L2E 7.2134752044448170f   // 5 * log2(e)
#define NROWS 4096
#define DDIM 256
#define MM 8192

typedef __bf16 bf16x8 __attribute__((ext_vector_type(8)));
typedef float f32x4 __attribute__((ext_vector_type(4)));

typedef const void __attribute__((address_space(1)))* gas_ptr;
typedef void __attribute__((address_space(3)))* las_ptr;

// ------- normalize rows of [Z1;Z2] -> unit L2, store bf16; zero rowsumAcc -------
__global__ __launch_bounds__(256, 2)
void nrm_kernel(const float* __restrict__ Z1, const float* __restrict__ Z2,
                unsigned short* __restrict__ Zb, float* __restrict__ rowsumAcc) {
    if (blockIdx.x < 32) rowsumAcc[blockIdx.x * 256 + threadIdx.x] = 0.f;
    const int w = threadIdx.x >> 6, lane = threadIdx.x & 63;
    const int row = blockIdx.x * 4 + w;
    const float* src = row < NROWS ? Z1 + (size_t)row * DDIM
                                   : Z2 + (size_t)(row - NROWS) * DDIM;
    float4 v = reinterpret_cast<const float4*>(src)[lane];
    float ss = v.x*v.x + v.y*v.y + v.z*v.z + v.w*v.w;
    #pragma unroll
    for (int m = 1; m < 64; m <<= 1) ss += __shfl_xor(ss, m, 64);
    float inv = 1.0f / fmaxf(sqrtf(ss), 1e-12f);
    float o[4] = { v.x*inv, v.y*inv, v.z*inv, v.w*inv };
    unsigned short us[4];
    #pragma unroll
    for (int e = 0; e < 4; ++e) {           // RNE f32->bf16 (finite inputs)
        unsigned int b = __builtin_bit_cast(unsigned int, o[e]);
        b += 0x7FFFu + ((b >> 16) & 1u);
        us[e] = (unsigned short)(b >> 16);
    }
    reinterpret_cast<ushort4*>(Zb + (size_t)row * DDIM)[lane] =
        *reinterpret_cast<ushort4*>(us);
}

// ---- stage 64 rows x 512B (32KB) into LDS with 256 threads; source pre-swizzled ----
// read side uses phys_inrow = inrow ^ ((row&15)<<4)
__device__ __forceinline__ void stage32(const unsigned short* Zb, char* ldsdst,
                                        int rowStart, int tid) {
    const char* base = reinterpret_cast<const char*>(Zb) + (size_t)rowStart * 512;
    #pragma unroll
    for (int it = 0; it < 8; ++it) {
        int L = it * 4096 + tid * 16;     // linear LDS byte offset, lane-contiguous
        int row = L >> 9;                 // 0..63
        int soff = row * 512 + ((L & 511) ^ ((row & 15) << 4));
        __builtin_amdgcn_global_load_lds((gas_ptr)(base + soff), (las_ptr)(ldsdst + L),
                                         16, 0, 0);
    }
}

// -------- symmetric fused sim + exp-rowsum/colsum + pos extraction --------
// Bands of 128 rows (64 bands). Block (r,s): band r, d-offsets {s,s+8,s+16,s+24}
// (each a 128x128 tile vs band (r+d)%64, as 2 x 64-col subtiles), plus (2 of 8
// splits) one half of the d=32 tile (rowsum-only, pos col i^4096 lives there).
// d=0: diagonal tile, rowsum-only, skip j==i. d=1..31: rowsum AND colsum
// (symmetry: colsums of the tile = rowsum contributions for band (r+d)).
// NO in-loop atomics: colsums accumulate in colPartLds[w][t][64] (each slot
// written exactly once by its owner wave), flushed once after the loop.
__global__ __launch_bounds__(256, 2)
void sim_lse_kernel(const unsigned short* __restrict__ Zb,
                    float* __restrict__ rowsumAcc,  // [MM], atomic accum
                    float* __restrict__ posArr) {   // [MM]
    __shared__ char lds[65536];                     // 2 x 32KB B buffers
    __shared__ float colPartLds[4][8][64];          // 8 KB colsum partials
    const int tid = threadIdx.x;
    const int lane = tid & 63;
    const int w = tid >> 6;
    const int r15 = lane & 15, hi = lane >> 4;
    const int r = blockIdx.x >> 3;                  // band 0..63
    const int s = blockIdx.x & 7;                   // split 0..7
    const int e0 = r & 7, e1 = e0 ^ 4;              // which splits take d=32 halves
    const int nt = 8 + ((s == e0) || (s == e1));
    const int extraHalf = (s == e1) ? 1 : 0;
    const int R0 = r * 128;

    // diag phases (s==0, t<2) never write colsums: zero own-wave slots
    if (s == 0) {
        colPartLds[w][0][lane] = 0.f;               // lane 0..63
        colPartLds[w][1][lane] = 0.f;
    }

    // thread-constant swizzled k-chunk offsets (row&15 == r15 for every frag read)
    int koff[8];
    #pragma unroll
    for (int kk = 0; kk < 8; ++kk)
        koff[kk] = ((hi << 4) | (kk << 6)) ^ (r15 << 4);

    // ---- stage A band (128 rows) across both buffers, pull frags to registers ----
    stage32(Zb, lds, R0, tid);
    stage32(Zb, lds + 32768, R0 + 64, tid);
    __syncthreads();
    bf16x8 qf[2][8];
    {
        const char* ab = lds + ((w >> 1) << 15);
        #pragma unroll
        for (int mf = 0; mf < 2; ++mf)
            #pragma unroll
            for (int kk = 0; kk < 8; ++kk)
                qf[mf][kk] = *reinterpret_cast<const bf16x8*>(
                    ab + ((w & 1) * 32 + mf * 16 + r15) * 512 + koff[kk]);
    }
    __syncthreads();

    int baddr[8];
    #pragma unroll
    for (int kk = 0; kk < 8; ++kk) baddr[kk] = r15 * 512 + koff[kk];

    float rowsum[2][4] = {{0,0,0,0},{0,0,0,0}};
    const int iBase = R0 + w * 32 + (hi << 2);      // C/D: row=(lane>>4)*4+rr

    // column start (Zb row units) of subtile step t
    auto colOf = [&](int t) -> int {
        int d = (t < 8) ? (s + ((t >> 1) << 3)) : 32;
        int half = (t < 8) ? (t & 1) : extraHalf;
        return ((r + d) & 63) * 128 + half * 64;
    };

    stage32(Zb, lds, colOf(0), tid);                // subtile 0 -> buf0

    for (int t = 0; t < nt; ++t) {
        const int C0 = colOf(t);
        const int cur = (t & 1) << 15;
        if (t < nt - 1) {
            stage32(Zb, lds + (cur ^ 32768), colOf(t + 1), tid);
            asm volatile("s_waitcnt vmcnt(8)" ::: "memory");   // cur's 8 loads done
        } else {
            asm volatile("s_waitcnt vmcnt(0)" ::: "memory");
        }
        __builtin_amdgcn_s_barrier();
        __builtin_amdgcn_sched_barrier(0);

        const int mode = (t == 8) ? 2 : ((s == 0 && t < 2) ? 1 : 0); // 0 norm,1 diag,2 pos
        #pragma unroll
        for (int nf = 0; nf < 4; ++nf) {
            f32x4 acc0 = {0,0,0,0}, acc1 = {0,0,0,0};
            #pragma unroll
            for (int kk = 0; kk < 8; ++kk) {
                bf16x8 b = *reinterpret_cast<const bf16x8*>(lds + cur + nf * 8192 + baddr[kk]);
                acc0 = __builtin_amdgcn_mfma_f32_16x16x32_bf16(qf[0][kk], b, acc0, 0, 0, 0);
                acc1 = __builtin_amdgcn_mfma_f32_16x16x32_bf16(qf[1][kk], b, acc1, 0, 0, 0);
            }
            const int j = C0 + nf * 16 + r15;       // C/D: col=lane&15
            if (mode == 0) {
                float s8 = 0.f;
                #pragma unroll
                for (int mf = 0; mf < 2; ++mf) {
                    const f32x4 a = mf ? acc1 : acc0;
                    #pragma unroll
                    for (int rr = 0; rr < 4; ++rr) {
                        float e = __builtin_amdgcn_exp2f(fmaf(a[rr], C5L2E, -C5L2E));
                        rowsum[mf][rr] += e;
                        s8 += e;
                    }
                }
                s8 += __shfl_xor(s8, 16, 64);       // sum the 4 hi-groups (32 rows)
                s8 += __shfl_xor(s8, 32, 64);
                if (hi == 0) colPartLds[w][t][(t & 1) * 0 + nf * 16 + r15] = s8; // unique slot
            } else if (mode == 1) {
                #pragma unroll
                for (int mf = 0; mf < 2; ++mf) {
                    const f32x4 a = mf ? acc1 : acc0;
                    #pragma unroll
                    for (int rr = 0; rr < 4; ++rr) {
                        const int i = iBase + mf * 16 + rr;
                        if (j != i)
                            rowsum[mf][rr] += __builtin_amdgcn_exp2f(fmaf(a[rr], C5L2E, -C5L2E));
                    }
                }
            } else {
                #pragma unroll
                for (int mf = 0; mf < 2; ++mf) {
                    const f32x4 a = mf ? acc1 : acc0;
                    #pragma unroll
                    for (int rr = 0; rr < 4; ++rr) {
                        const int i = iBase + mf * 16 + rr;
                        rowsum[mf][rr] += __builtin_amdgcn_exp2f(fmaf(a[rr], C5L2E, -C5L2E));
                        if (j == (i ^ 4096)) posArr[i] = a[rr] * TINV;  // unique writer
                    }
                }
            }
        }
        asm volatile("" ::: "memory");
        __builtin_amdgcn_sched_barrier(0);
        __builtin_amdgcn_s_barrier();               // done reading cur before overwrite
    }

    // ---- one-time colsum flush: combine 4 waves, 512 targets = 2 per thread ----
    __syncthreads();                                // colPartLds writes visible
    #pragma unroll
    for (int z = 0; z < 2; ++z) {
        const int idx = z * 256 + tid;              // t*64 + c
        const int tt = idx >> 6, c = idx & 63;
        float v = colPartLds[0][tt][c] + colPartLds[1][tt][c]
                + colPartLds[2][tt][c] + colPartLds[3][tt][c];
        if (v != 0.f) atomicAdd(&rowsumAcc[colOf(tt) + c], v);
    }

    // reduce rowsums across the 16 lanes sharing each row, flush atomically
    #pragma unroll
    for (int mf = 0; mf < 2; ++mf)
        #pragma unroll
        for (int rr = 0; rr < 4; ++rr) {
            float v = rowsum[mf][rr];
            v += __shfl_xor(v, 1, 64);
            v += __shfl_xor(v, 2, 64);
            v += __shfl_xor(v, 4, 64);
            v += __shfl_xor(v, 8, 64);
            if (r15 == 0) atomicAdd(&rowsumAcc[iBase + mf * 16 + rr], v);
        }
}

// ---------------- finish: lse = log(sum)+5; mean(lse - pos) ----------------
__global__ __launch_bounds__(128)
void fin1_kernel(const float* __restrict__ rowsumAcc, const float* __restrict__ posArr,
                 float* __restrict__ blockSums) {    // [64]
    const int tid = threadIdx.x;
    const int i = blockIdx.x * 128 + tid;
    double v = (double)(logf(rowsumAcc[i]) + 5.0f - posArr[i]);
    #pragma unroll
    for (int m = 1; m < 64; m <<= 1) v += __shfl_xor(v, m, 64);
    __shared__ double red[2];
    if ((tid & 63) == 0) red[tid >> 6] = v;
    __syncthreads();
    if (tid == 0) blockSums[blockIdx.x] = (float)(red[0] + red[1]);
}

__global__ __launch_bounds__(64)
void fin2_kernel(const float* __restrict__ blockSums, float* __restrict__ out) {
    double v = (double)blockSums[threadIdx.x];
    #pragma unroll
    for (int m = 1; m < 64; m <<= 1) v += __shfl_xor(v, m, 64);
    if (threadIdx.x == 0) out[0] = (float)(v / (double)MM);
}

extern "C" void kernel_launch(void* const* d_in, const int* in_sizes, int n_in,
                              void* d_out, int out_size, void* d_ws, size_t ws_size,
                              hipStream_t stream) {
    const float* Z1 = (const float*)d_in[0];
    const float* Z2 = (const float*)d_in[1];
    float* out = (float*)d_out;
    char* ws = (char*)d_ws;
    unsigned short* Zb = (unsigned short*)ws;                         // 4 MB bf16 [8192][256]
    float* posArr = (float*)(ws + 4194304);                           // 32 KB
    float* rowsumAcc = (float*)(ws + 4194304 + 32768);                // 32 KB
    float* blockSums = (float*)(ws + 4194304 + 65536);                // 256 B

    nrm_kernel<<<MM / 4, 256, 0, stream>>>(Z1, Z2, Zb, rowsumAcc);
    sim_lse_kernel<<<64 * 8, 256, 0, stream>>>(Zb, rowsumAcc, posArr);
    fin1_kernel<<<64, 128, 0, stream>>>(rowsumAcc, posArr, blockSums);
    fin2_kernel<<<1, 64, 0, stream>>>(blockSums, out);
}

// Round 11
// 42.532 us; speedup vs baseline: 1.5532x; 1.0184x over previous
//
#include <hip/hip_runtime.h>
#include <cstdint>
#include <cstddef>

#define TINV 5.0f
#define C5L2E 7.2134752044448170f   // 5 * log2(e)
#define NROWS 4096
#define DDIM 256
#define MM 8192

typedef __bf16 bf16x8 __attribute__((ext_vector_type(8)));
typedef int i32x4 __attribute__((ext_vector_type(4)));
typedef float f32x4 __attribute__((ext_vector_type(4)));

typedef const void __attribute__((address_space(1)))* gas_ptr;
typedef void __attribute__((address_space(3)))* las_ptr;

// ------- normalize rows of [Z1;Z2] -> unit L2, store bf16; zero rowsumAcc -------
__global__ __launch_bounds__(256, 2)
void nrm_kernel(const float* __restrict__ Z1, const float* __restrict__ Z2,
                unsigned short* __restrict__ Zb, float* __restrict__ rowsumAcc) {
    if (blockIdx.x < 32) rowsumAcc[blockIdx.x * 256 + threadIdx.x] = 0.f;
    const int w = threadIdx.x >> 6, lane = threadIdx.x & 63;
    const int row = blockIdx.x * 4 + w;
    const float* src = row < NROWS ? Z1 + (size_t)row * DDIM
                                   : Z2 + (size_t)(row - NROWS) * DDIM;
    float4 v = reinterpret_cast<const float4*>(src)[lane];
    float ss = v.x*v.x + v.y*v.y + v.z*v.z + v.w*v.w;
    #pragma unroll
    for (int m = 1; m < 64; m <<= 1) ss += __shfl_xor(ss, m, 64);
    float inv = 1.0f / fmaxf(sqrtf(ss), 1e-12f);
    float o[4] = { v.x*inv, v.y*inv, v.z*inv, v.w*inv };
    unsigned short us[4];
    #pragma unroll
    for (int e = 0; e < 4; ++e) {           // RNE f32->bf16 (finite inputs)
        unsigned int b = __builtin_bit_cast(unsigned int, o[e]);
        b += 0x7FFFu + ((b >> 16) & 1u);
        us[e] = (unsigned short)(b >> 16);
    }
    reinterpret_cast<ushort4*>(Zb + (size_t)row * DDIM)[lane] =
        *reinterpret_cast<ushort4*>(us);
}

// ---- stage 64 rows x 512B (32KB) into LDS with 256 threads; source pre-swizzled ----
// read side uses phys_inrow = inrow ^ ((row&15)<<4)
__device__ __forceinline__ void stage32(const unsigned short* Zb, char* ldsdst,
                                        int rowStart, int tid) {
    const char* base = reinterpret_cast<const char*>(Zb) + (size_t)rowStart * 512;
    #pragma unroll
    for (int it = 0; it < 8; ++it) {
        int L = it * 4096 + tid * 16;     // linear LDS byte offset, lane-contiguous
        int row = L >> 9;                 // 0..63
        int soff = row * 512 + ((L & 511) ^ ((row & 15) << 4));
        __builtin_amdgcn_global_load_lds((gas_ptr)(base + soff), (las_ptr)(ldsdst + L),
                                         16, 0, 0);
    }
}

// -------- symmetric fused sim + exp-rowsum/colsum + pos extraction --------
// Same schedule as R10 (64 bands x 128 rows, 8 splits, d-offsets {s,s+8,s+16,s+24},
// d=32 halves on 2 splits; colsums via symmetry into colPartLds, no in-loop atomics).
// ONE change: 2x2 wave grid. Wave (wr,wc) owns 64 rows x 32 cols; A-frags (32 x
// i32x4) held in AGPRs via asm "a" constraint -> B LDS reads per phase HALVED.
__global__ __launch_bounds__(256, 2)
void sim_lse_kernel(const unsigned short* __restrict__ Zb,
                    float* __restrict__ rowsumAcc,  // [MM], atomic accum
                    float* __restrict__ posArr) {   // [MM]
    __shared__ char lds[65536];                     // 2 x 32KB B buffers
    __shared__ float colPartLds[4][8][32];          // 4 KB colsum partials
    const int tid = threadIdx.x;
    const int lane = tid & 63;
    const int w = tid >> 6;
    const int wr = w >> 1, wc = w & 1;              // wave row-group / col-half
    const int r15 = lane & 15, hi = lane >> 4;
    const int r = blockIdx.x >> 3;                  // band 0..63
    const int s = blockIdx.x & 7;                   // split 0..7
    const int e0 = r & 7, e1 = e0 ^ 4;              // which splits take d=32 halves
    const int nt = 8 + ((s == e0) || (s == e1));
    const int extraHalf = (s == e1) ? 1 : 0;
    const int R0 = r * 128;

    // diag phases (s==0, t<2) never write colsums: zero own-wave slots
    if (s == 0 && lane < 32) {
        colPartLds[w][0][lane] = 0.f;
        colPartLds[w][1][lane] = 0.f;
    }

    // thread-constant swizzled k-chunk offsets (row&15 == r15 for every frag read)
    int koff[8];
    #pragma unroll
    for (int kk = 0; kk < 8; ++kk)
        koff[kk] = ((hi << 4) | (kk << 6)) ^ (r15 << 4);

    // ---- stage A band (128 rows) across both buffers, pull frags to registers ----
    stage32(Zb, lds, R0, tid);
    stage32(Zb, lds + 32768, R0 + 64, tid);
    __syncthreads();
    i32x4 qf[4][8];                                 // 64 rows x K=256 -> AGPRs
    {
        const char* ab = lds + (wr << 15);          // wr: which 64-row buffer
        #pragma unroll
        for (int mf = 0; mf < 4; ++mf)
            #pragma unroll
            for (int kk = 0; kk < 8; ++kk)
                qf[mf][kk] = *reinterpret_cast<const i32x4*>(
                    ab + (mf * 16 + r15) * 512 + koff[kk]);
    }
    __syncthreads();

    int baddr[8];                                   // wave's 32-col half of B tile
    #pragma unroll
    for (int kk = 0; kk < 8; ++kk)
        baddr[kk] = (wc * 32 + r15) * 512 + koff[kk];

    float rowsum[4][4] = {{0,0,0,0},{0,0,0,0},{0,0,0,0},{0,0,0,0}};
    const int iBase = R0 + wr * 64 + (hi << 2);     // C/D: row=(lane>>4)*4+rr

    // column start (Zb row units) of subtile step t
    auto colOf = [&](int t) -> int {
        int d = (t < 8) ? (s + ((t >> 1) << 3)) : 32;
        int half = (t < 8) ? (t & 1) : extraHalf;
        return ((r + d) & 63) * 128 + half * 64;
    };

    stage32(Zb, lds, colOf(0), tid);                // subtile 0 -> buf0

    for (int t = 0; t < nt; ++t) {
        const int C0 = colOf(t);
        const int cur = (t & 1) << 15;
        if (t < nt - 1) {
            stage32(Zb, lds + (cur ^ 32768), colOf(t + 1), tid);
            asm volatile("s_waitcnt vmcnt(8)" ::: "memory");   // cur's 8 loads done
        } else {
            asm volatile("s_waitcnt vmcnt(0)" ::: "memory");
        }
        __builtin_amdgcn_s_barrier();
        __builtin_amdgcn_sched_barrier(0);

        const int mode = (t == 8) ? 2 : ((s == 0 && t < 2) ? 1 : 0); // 0 norm,1 diag,2 pos
        #pragma unroll
        for (int nf = 0; nf < 2; ++nf) {
            f32x4 acc[4] = {{0,0,0,0},{0,0,0,0},{0,0,0,0},{0,0,0,0}};
            #pragma unroll
            for (int kk = 0; kk < 8; ++kk) {
                i32x4 b = *reinterpret_cast<const i32x4*>(lds + cur + nf * 8192 + baddr[kk]);
                #pragma unroll
                for (int mf = 0; mf < 4; ++mf)
                    asm("v_mfma_f32_16x16x32_bf16 %0, %1, %2, %0"
                        : "+v"(acc[mf]) : "a"(qf[mf][kk]), "v"(b));
            }
            const int j = C0 + wc * 32 + nf * 16 + r15;   // C/D: col=lane&15
            if (mode == 0) {
                float s8 = 0.f;
                #pragma unroll
                for (int mf = 0; mf < 4; ++mf)
                    #pragma unroll
                    for (int rr = 0; rr < 4; ++rr) {
                        float e = __builtin_amdgcn_exp2f(fmaf(acc[mf][rr], C5L2E, -C5L2E));
                        rowsum[mf][rr] += e;
                        s8 += e;
                    }
                s8 += __shfl_xor(s8, 16, 64);       // sum the 4 hi-groups (64 rows)
                s8 += __shfl_xor(s8, 32, 64);
                if (hi == 0) colPartLds[w][t][nf * 16 + r15] = s8;  // unique slot
            } else if (mode == 1) {
                #pragma unroll
                for (int mf = 0; mf < 4; ++mf)
                    #pragma unroll
                    for (int rr = 0; rr < 4; ++rr) {
                        const int i = iBase + mf * 16 + rr;
                        if (j != i)
                            rowsum[mf][rr] += __builtin_amdgcn_exp2f(fmaf(acc[mf][rr], C5L2E, -C5L2E));
                    }
            } else {
                #pragma unroll
                for (int mf = 0; mf < 4; ++mf)
                    #pragma unroll
                    for (int rr = 0; rr < 4; ++rr) {
                        const int i = iBase + mf * 16 + rr;
                        rowsum[mf][rr] += __builtin_amdgcn_exp2f(fmaf(acc[mf][rr], C5L2E, -C5L2E));
                        if (j == (i ^ 4096)) posArr[i] = acc[mf][rr] * TINV;  // unique
                    }
            }
        }
        asm volatile("" ::: "memory");
        __builtin_amdgcn_sched_barrier(0);
        __builtin_amdgcn_s_barrier();               // done reading cur before overwrite
    }

    // ---- one-time colsum flush: 8 tiles x 64 cols = 512 targets = 2/thread ----
    __syncthreads();                                // colPartLds writes visible
    #pragma unroll
    for (int z = 0; z < 2; ++z) {
        const int idx = z * 256 + tid;              // t*64 + c
        const int tt = idx >> 6, c = idx & 63;
        const int ww = c >> 5;                      // which wc owns column c
        float v = colPartLds[ww][tt][c & 31] + colPartLds[2 + ww][tt][c & 31];
        if (v != 0.f) atomicAdd(&rowsumAcc[colOf(tt) + c], v);
    }

    // reduce rowsums across the 16 lanes sharing each row, flush atomically
    // (each row gets adds from both wc waves)
    #pragma unroll
    for (int mf = 0; mf < 4; ++mf)
        #pragma unroll
        for (int rr = 0; rr < 4; ++rr) {
            float v = rowsum[mf][rr];
            v += __shfl_xor(v, 1, 64);
            v += __shfl_xor(v, 2, 64);
            v += __shfl_xor(v, 4, 64);
            v += __shfl_xor(v, 8, 64);
            if (r15 == 0) atomicAdd(&rowsumAcc[iBase + mf * 16 + rr], v);
        }
}

// ---------------- finish: lse = log(sum)+5; mean(lse - pos) ----------------
__global__ __launch_bounds__(128)
void fin1_kernel(const float* __restrict__ rowsumAcc, const float* __restrict__ posArr,
                 float* __restrict__ blockSums) {    // [64]
    const int tid = threadIdx.x;
    const int i = blockIdx.x * 128 + tid;
    double v = (double)(logf(rowsumAcc[i]) + 5.0f - posArr[i]);
    #pragma unroll
    for (int m = 1; m < 64; m <<= 1) v += __shfl_xor(v, m, 64);
    __shared__ double red[2];
    if ((tid & 63) == 0) red[tid >> 6] = v;
    __syncthreads();
    if (tid == 0) blockSums[blockIdx.x] = (float)(red[0] + red[1]);
}

__global__ __launch_bounds__(64)
void fin2_kernel(const float* __restrict__ blockSums, float* __restrict__ out) {
    double v = (double)blockSums[threadIdx.x];
    #pragma unroll
    for (int m = 1; m < 64; m <<= 1) v += __shfl_xor(v, m, 64);
    if (threadIdx.x == 0) out[0] = (float)(v / (double)MM);
}

extern "C" void kernel_launch(void* const* d_in, const int* in_sizes, int n_in,
                              void* d_out, int out_size, void* d_ws, size_t ws_size,
                              hipStream_t stream) {
    const float* Z1 = (const float*)d_in[0];
    const float* Z2 = (const float*)d_in[1];
    float* out = (float*)d_out;
    char* ws = (char*)d_ws;
    unsigned short* Zb = (unsigned short*)ws;                         // 4 MB bf16 [8192][256]
    float* posArr = (float*)(ws + 4194304);                           // 32 KB
    float* rowsumAcc = (float*)(ws + 4194304 + 32768);                // 32 KB
    float* blockSums = (float*)(ws + 4194304 + 65536);                // 256 B

    nrm_kernel<<<MM / 4, 256, 0, stream>>>(Z1, Z2, Zb, rowsumAcc);
    sim_lse_kernel<<<64 * 8, 256, 0, stream>>>(Zb, rowsumAcc, posArr);
    fin1_kernel<<<64, 128, 0, stream>>>(rowsumAcc, posArr, blockSums);
    fin2_kernel<<<1, 64, 0, stream>>>(blockSums, out);
}